// Round 13
// baseline (170.270 us; speedup 1.0000x reference)
//
#include <hip/hip_runtime.h>

#define NQ 12
#define NL 4
#define NGATES (NQ * NL)
#define INV_2PI 0.15915494309189535f

// ---------------------------------------------------------------------------
// Diagonalized formulation. Every compiled gate is exp(-i th/2 X_m) (XOR-mask
// pairing, symmetric update) -> all 48 commute; conjugating by H^x12 makes
// the WHOLE circuit diagonal:  U = H D H,  D|q> = e^{-iPhi(q)}|q>,
//   Phi(q) = sum_g (th_g/2) * (-1)^{parity(q & m_g)}   (all 48 gates; layer-1
//   folds in too: H RX(th) RY(x)|0> = real(bit) * phase(bit)).
// <Z_w> = sum_q conj(psi(q^rho_w)) psi(q), rho_w = row of L^-1 (HZH = X).
// psi(q) = A(q) e^{-iPhi(q)}; A REAL product state: a0 = cy+sy, a1 = cy-sy
// per qubit (global scale 2^-6).
// Layout (A = I): p[4:0]=reg (qubits 11..7), p[10:5]=lane (qubits 6..1),
// p[11]=wave (qubit 0). 128 thr/elem, 32 amps/thread.
// LIVENESS ORDER (round-12 spilled 660 MB from W+A+a0a1 all live):
//   1) a0/a1 -> A[32] doubling (a dies; peak 56)
//   2) W[32] accum + 5-bit WHT   (A+W = 64 live)
//   3) st[r] = (A c, -A s)       (A, W die into st; peak ~64)
//   4) correlations              (st 64 + acc 10)
// sched_barrier(0) between phases pins this order (r6 lesson).
// Correlations: cheap lane masks via DPP/permlane; wave-crossing/expensive
// masks via 2-chunk LDS stash (16 KB, 3 barriers) on the idle DS pipe.
// ---------------------------------------------------------------------------
struct Masks { unsigned rx[NGATES]; unsigned z[NQ]; };

constexpr Masks compute_masks() {
  Masks mk{};
  unsigned col[NQ] = {};
  for (int b = 0; b < NQ; ++b) col[b] = 1u << b;
  int g = 0;
  for (int l = 0; l < NL; ++l) {
    for (int w = 0; w < NQ; ++w) mk.rx[g++] = col[NQ - 1 - w];
    for (int i = 0; i < NQ; ++i) {           // ring CNOT(i, (i+1)%12)
      int cb = NQ - 1 - i;
      int tb = NQ - 1 - ((i + 1) % NQ);
      col[cb] ^= col[tb];
    }
  }
  unsigned A[NQ] = {}, Inv[NQ] = {};
  for (int i = 0; i < NQ; ++i) {
    unsigned rowv = 0;
    for (int j = 0; j < NQ; ++j) rowv |= ((col[j] >> i) & 1u) << j;
    A[i] = rowv;
    Inv[i] = 1u << i;
  }
  for (int c = 0; c < NQ; ++c) {
    int piv = c;
    while (((A[piv] >> c) & 1u) == 0u) ++piv;
    unsigned ta = A[piv]; A[piv] = A[c]; A[c] = ta;
    unsigned ti = Inv[piv]; Inv[piv] = Inv[c]; Inv[c] = ti;
    for (int r = 0; r < NQ; ++r)
      if (r != c && ((A[r] >> c) & 1u)) { A[r] ^= A[c]; Inv[r] ^= Inv[c]; }
  }
  for (int w = 0; w < NQ; ++w) mk.z[w] = Inv[NQ - 1 - w];
  return mk;
}

constexpr Masks MK = compute_masks();

typedef float v2f __attribute__((ext_vector_type(2)));
typedef int   v2i __attribute__((ext_vector_type(2)));

template <int CTRL>
__device__ __forceinline__ int dpp_i(int x) {
  return __builtin_amdgcn_update_dpp(x, x, CTRL, 0xf, 0xf, false);
}

// VALU cost of a cross-lane xor-mask fetch (DPP/permlane path).
constexpr int dppcost(int ml) {
  int m4 = ml & 15;
  int c = (m4 == 0) ? 0
        : ((m4 == 1 || m4 == 2 || m4 == 3 || m4 == 7 || m4 == 8 || m4 == 15) ? 1 : 2);
  if (ml & 16) c += 2;
  if (ml & 32) c += 2;
  return c;
}

// v[lane ^ ML] on the VALU pipe. quad_perm xor1=0xB1 xor2=0x4E xor3=0x1B;
// row_half_mirror(xor7)=0x141; row_ror:8(xor8)=0x128; row_mirror(xor15)=0x140.
template <int ML>
__device__ __forceinline__ float fetchx(float v) {
  static_assert(ML >= 1 && ML < 64, "lane mask");
  int x = __float_as_int(v);
  constexpr int m4 = ML & 15;
  if constexpr (m4 == 1)       x = dpp_i<0xB1>(x);
  else if constexpr (m4 == 2)  x = dpp_i<0x4E>(x);
  else if constexpr (m4 == 3)  x = dpp_i<0x1B>(x);
  else if constexpr (m4 == 4)  { x = dpp_i<0x141>(x); x = dpp_i<0x1B>(x); }
  else if constexpr (m4 == 5)  { x = dpp_i<0x141>(x); x = dpp_i<0x4E>(x); }
  else if constexpr (m4 == 6)  { x = dpp_i<0x141>(x); x = dpp_i<0xB1>(x); }
  else if constexpr (m4 == 7)  x = dpp_i<0x141>(x);
  else if constexpr (m4 == 8)  x = dpp_i<0x128>(x);
  else if constexpr (m4 == 9)  { x = dpp_i<0x128>(x); x = dpp_i<0xB1>(x); }
  else if constexpr (m4 == 10) { x = dpp_i<0x128>(x); x = dpp_i<0x4E>(x); }
  else if constexpr (m4 == 11) { x = dpp_i<0x128>(x); x = dpp_i<0x1B>(x); }
  else if constexpr (m4 == 12) { x = dpp_i<0x140>(x); x = dpp_i<0x1B>(x); }
  else if constexpr (m4 == 13) { x = dpp_i<0x140>(x); x = dpp_i<0x4E>(x); }
  else if constexpr (m4 == 14) { x = dpp_i<0x140>(x); x = dpp_i<0xB1>(x); }
  else if constexpr (m4 == 15) x = dpp_i<0x140>(x);
  if constexpr (ML & 16) {
    v2i r = __builtin_amdgcn_permlane16_swap(x, x, false, false);
    x = (threadIdx.x & 16) ? r.x : r.y;
  }
  if constexpr (ML & 32) {
    v2i r = __builtin_amdgcn_permlane32_swap(x, x, false, false);
    x = (threadIdx.x & 32) ? r.x : r.y;
  }
  return __int_as_float(x);
}

// 64-lane sum of acc.x + acc.y.
__device__ __forceinline__ float redl(v2f acc) {
  float s = acc.x + acc.y;
  {
    v2i r = __builtin_amdgcn_permlane32_swap(__float_as_int(s),
                                             __float_as_int(s), false, false);
    s = __int_as_float(r.x) + __int_as_float(r.y);
  }
  {
    v2i r = __builtin_amdgcn_permlane16_swap(__float_as_int(s),
                                             __float_as_int(s), false, false);
    s = __int_as_float(r.x) + __int_as_float(r.y);
  }
  s += fetchx<8>(s);
  s += fetchx<4>(s);
  s += fetchx<2>(s);
  s += fetchx<1>(s);
  return s;
}

// Accumulate +-th_g into W[m_g & 31]; sign = parity(tid & (lane|wave bits)).
template <int G>
__device__ __forceinline__ void accum_signs(float (&W)[32],
                                            const float* __restrict__ phi,
                                            int tid) {
  if constexpr (G < NGATES) {
    constexpr unsigned m = MK.rx[G];
    constexpr int mlo = (int)(m & 31u);
    constexpr int tmask = (int)(((m >> 5) & 63u) | (((m >> 11) & 1u) << 6));
    const float th = phi[G];                 // uniform -> s_load, SGPR
    if constexpr (tmask == 0) {
      W[mlo] += th;
    } else {
      const int sgn = (__popc(tid & tmask) & 1) << 31;
      W[mlo] += __int_as_float(__float_as_int(th) ^ sgn);
    }
    accum_signs<G + 1>(W, phi, tid);
  }
}

// Is correlation lag w handled via the LDS stash?
constexpr bool is_lds(int w) {
  unsigned zm = MK.z[w];
  int ml = (int)((zm >> 5) & 63u);
  int mw = (int)((zm >> 11) & 1u);
  return mw != 0 || dppcost(ml) > 2;
}

// Cheap lags: partner via DPP/permlane, full 32-amp dot, reduce, store.
template <int W_>
__device__ __forceinline__ void corr_dpp(const v2f (&st)[32], float* zb,
                                         int lane, int wv) {
  if constexpr (W_ < NQ) {
    if constexpr (!is_lds(W_)) {
      constexpr unsigned zm = MK.z[W_];
      constexpr int mr = (int)(zm & 31u);
      constexpr int ml = (int)((zm >> 5) & 63u);
      v2f acc; acc.x = 0.f; acc.y = 0.f;
#pragma unroll
      for (int r = 0; r < 32; ++r) {
        v2f t;
        if constexpr (ml == 0) t = st[r ^ mr];
        else { t.x = fetchx<ml>(st[r ^ mr].x); t.y = fetchx<ml>(st[r ^ mr].y); }
        acc += st[r] * t;                    // v_pk_fma_f32
      }
      float s = redl(acc);
      if (lane == 0) zb[wv * NQ + W_] = s;
    }
    corr_dpp<W_ + 1>(st, zb, lane, wv);
  }
}

// LDS-stash lags: stash chunk CH holds regs [16CH,16CH+16); slot k serves
// local reg (16CH+k)^mr. Partner thread = tid ^ (wave?64) ^ ml.
template <int CH, int W_>
__device__ __forceinline__ void corr_lds_chunk(const v2f (&st)[32],
                                               v2f (&acc)[NQ],
                                               const v2f* xbuf, int tid) {
  if constexpr (W_ < NQ) {
    if constexpr (is_lds(W_)) {
      constexpr unsigned zm = MK.z[W_];
      constexpr int mr = (int)(zm & 31u);
      constexpr int ml = (int)((zm >> 5) & 63u);
      constexpr int mw = (int)((zm >> 11) & 1u);
      const int ptid = tid ^ (mw ? 64 : 0) ^ ml;
#pragma unroll
      for (int k = 0; k < 16; ++k) {
        const int r = (CH * 16 + k) ^ mr;
        acc[W_] += st[r] * xbuf[k * 128 + ptid];
      }
    }
    corr_lds_chunk<CH, W_ + 1>(st, acc, xbuf, tid);
  }
}

template <int W_>
__device__ __forceinline__ void corr_lds_emit(v2f (&acc)[NQ], float* zb,
                                              int lane, int wv) {
  if constexpr (W_ < NQ) {
    if constexpr (is_lds(W_)) {
      float s = redl(acc[W_]);
      if (lane == 0) zb[wv * NQ + W_] = s;
    }
    corr_lds_emit<W_ + 1>(acc, zb, lane, wv);
  }
}

// Prep: 48 batch-uniform gate angles -> th_g/(4pi) (revolutions of th/2).
__global__ void prep_kernel(const float* __restrict__ wts,
                            float* __restrict__ phi) {
  const int i = threadIdx.x;
  if (i < NGATES) phi[i] = wts[i] * (0.5f * INV_2PI);
}

__global__ __attribute__((amdgpu_flat_work_group_size(128, 128),
                          amdgpu_waves_per_eu(3)))
void qsim_kernel(const float* __restrict__ x,
                 const float* __restrict__ phi,
                 float* __restrict__ out) {
  __shared__ v2f xbuf[16 * 128];       // 16 KiB correlation stash
  __shared__ float zb[2 * NQ];

  const int bidx = blockIdx.x;         // one batch element per 128-thr block
  const int tid  = threadIdx.x;
  const int lane = tid & 63;
  const int wv   = tid >> 6;

  const float4* xv = reinterpret_cast<const float4*>(x + bidx * NQ);
  float4 q0 = xv[0], q1 = xv[1], q2 = xv[2];
  const float xa[NQ] = {q0.x, q0.y, q0.z, q0.w, q1.x, q1.y, q1.z, q1.w,
                        q2.x, q2.y, q2.z, q2.w};

  // ---- Phase 1: REAL product amplitude A (a0 = cy+sy, a1 = cy-sy).
  // Scalar part (qubit 0 = wave, 1..6 = lane bits), consumed immediately.
  float A[32];
  {
    float rv = xa[0] * (0.5f * INV_2PI);
    float sy = __builtin_amdgcn_sinf(rv), cy = __builtin_amdgcn_cosf(rv);
    float F = 0.015625f * (wv ? (cy - sy) : (cy + sy));   // 2^-6 norm
#pragma unroll
    for (int w = 1; w <= 6; ++w) {
      rv = xa[w] * (0.5f * INV_2PI);
      sy = __builtin_amdgcn_sinf(rv); cy = __builtin_amdgcn_cosf(rv);
      const int b = (lane >> (6 - w)) & 1;
      F *= b ? (cy - sy) : (cy + sy);
    }
    A[0] = F;
#pragma unroll
    for (int j = 0; j < 5; ++j) {                // reg bit j = qubit 11-j
      const int wq = 11 - j;
      rv = xa[wq] * (0.5f * INV_2PI);
      sy = __builtin_amdgcn_sinf(rv); cy = __builtin_amdgcn_cosf(rv);
      const float g0 = cy + sy, g1 = cy - sy;
#pragma unroll
      for (int k = 0; k < 16; ++k) {
        if (k < (1 << j)) {
          float base = A[k];
          A[k | (1 << j)] = base * g1;
          A[k]            = base * g0;
        }
      }
    }
  }
  __builtin_amdgcn_sched_barrier(0);

  // ---- Phase 2: Phi via signed accumulation + 5-bit WHT over reg coords.
  float W[32];
#pragma unroll
  for (int k = 0; k < 32; ++k) W[k] = 0.f;
  accum_signs<0>(W, phi, tid);
#pragma unroll
  for (int j = 0; j < 5; ++j) {
#pragma unroll
    for (int k = 0; k < 32; ++k) {
      if (!(k & (1 << j))) {
        float a = W[k], b = W[k | (1 << j)];
        W[k]            = a + b;
        W[k | (1 << j)] = a - b;
      }
    }
  }
  __builtin_amdgcn_sched_barrier(0);

  // ---- Phase 3: psi = A e^{-i Phi}; A and W die into st.
  v2f st[32];
#pragma unroll
  for (int r = 0; r < 32; ++r) {
    float s = __builtin_amdgcn_sinf(W[r]);
    float c = __builtin_amdgcn_cosf(W[r]);
    st[r].x = A[r] * c;
    st[r].y = -A[r] * s;
  }
  __builtin_amdgcn_sched_barrier(0);

  // ---- Phase 4: <Z_w> = sum_q Re[psi*(q^rho_w) psi(q)].
  corr_dpp<0>(st, zb, lane, wv);

  v2f acc[NQ] = {};
#pragma unroll
  for (int k = 0; k < 16; ++k) xbuf[k * 128 + tid] = st[k];
  __syncthreads();
  corr_lds_chunk<0, 0>(st, acc, xbuf, tid);
  __syncthreads();                                // readers done; reuse buffer
#pragma unroll
  for (int k = 0; k < 16; ++k) xbuf[k * 128 + tid] = st[16 + k];
  __syncthreads();
  corr_lds_chunk<1, 0>(st, acc, xbuf, tid);
  corr_lds_emit<0>(acc, zb, lane, wv);

  __syncthreads();
  if (tid < NQ) out[bidx * NQ + tid] = zb[tid] + zb[NQ + tid];
}

extern "C" void kernel_launch(void* const* d_in, const int* in_sizes, int n_in,
                              void* d_out, int out_size, void* d_ws, size_t ws_size,
                              hipStream_t stream) {
  const float* x   = (const float*)d_in[0];   // (4096, 12) f32
  const float* wts = (const float*)d_in[1];   // (4, 12) f32
  float* out = (float*)d_out;                 // (4096, 12) f32
  float* phi = (float*)d_ws;                  // 48 floats: th/(4pi)

  prep_kernel<<<1, 64, 0, stream>>>(wts, phi);

  const int batch = in_sizes[0] / NQ;         // 4096
  dim3 grid(batch);
  dim3 block(128);
  qsim_kernel<<<grid, block, 0, stream>>>(x, phi, out);
}

// Round 14
// 78.239 us; speedup vs baseline: 2.1763x; 2.1763x over previous
//
#include <hip/hip_runtime.h>

#define NQ 12
#define NL 4
#define NGATES (NQ * NL)
#define INV_2PI 0.15915494309189535f

// ---------------------------------------------------------------------------
// Diagonalized formulation (round-12 algebra, 16 amps/thread to fit regs).
// Every compiled gate is exp(-i th/2 X_m) -> all 48 commute; conjugating by
// H^x12 diagonalizes the circuit: U = H D H, D|q> = e^{-iPhi(q)}|q>,
//   Phi(q) = sum_g (th_g/2)(-1)^{parity(q & m_g)}  (layer-1 included).
// <Z_w> = sum_q conj(psi(q^rho_w)) psi(q), rho_w = row of L^-1 (HZH = X);
// psi = A e^{-iPhi}, A real product state (a0 = cy+sy, a1 = cy-sy, scale 2^-6).
// Layout (A = I): p[3:0] = reg (qubits 11..8), p[9:4] = lane bits 0..5
// (qubits 7..2), p[10] = tid6 (qubit 1), p[11] = tid7 (qubit 0).
// 256 thr/elem, 16 amps/thread: st = 32 VGPR, A/W 16 each -> peak ~75 regs
// (round 12/13 kept 32 amps/thread: st alone = 64 > the 84-reg arch grant;
// the 12 corr passes re-read spilled st -> 660 MB of scratch traffic).
// Phi: accumulate +-phi_g into W[m&15] (sign = parity(tid & (m>>4))), 4-bit
// WHT, then st[r] = A[r](cos, -sin)(W[r]) via hw trig in revolutions.
// Correlations: cheap lane masks via DPP/permlane; others via ONE full LDS
// stash of st (32 KB, one barrier), each lag computed and retired in turn.
// ---------------------------------------------------------------------------
struct Masks { unsigned rx[NGATES]; unsigned z[NQ]; };

constexpr Masks compute_masks() {
  Masks mk{};
  unsigned col[NQ] = {};
  for (int b = 0; b < NQ; ++b) col[b] = 1u << b;
  int g = 0;
  for (int l = 0; l < NL; ++l) {
    for (int w = 0; w < NQ; ++w) mk.rx[g++] = col[NQ - 1 - w];
    for (int i = 0; i < NQ; ++i) {           // ring CNOT(i, (i+1)%12)
      int cb = NQ - 1 - i;
      int tb = NQ - 1 - ((i + 1) % NQ);
      col[cb] ^= col[tb];
    }
  }
  unsigned A[NQ] = {}, Inv[NQ] = {};
  for (int i = 0; i < NQ; ++i) {
    unsigned rowv = 0;
    for (int j = 0; j < NQ; ++j) rowv |= ((col[j] >> i) & 1u) << j;
    A[i] = rowv;
    Inv[i] = 1u << i;
  }
  for (int c = 0; c < NQ; ++c) {
    int piv = c;
    while (((A[piv] >> c) & 1u) == 0u) ++piv;
    unsigned ta = A[piv]; A[piv] = A[c]; A[c] = ta;
    unsigned ti = Inv[piv]; Inv[piv] = Inv[c]; Inv[c] = ti;
    for (int r = 0; r < NQ; ++r)
      if (r != c && ((A[r] >> c) & 1u)) { A[r] ^= A[c]; Inv[r] ^= Inv[c]; }
  }
  for (int w = 0; w < NQ; ++w) mk.z[w] = Inv[NQ - 1 - w];
  return mk;
}

constexpr Masks MK = compute_masks();

typedef float v2f __attribute__((ext_vector_type(2)));
typedef int   v2i __attribute__((ext_vector_type(2)));

template <int CTRL>
__device__ __forceinline__ int dpp_i(int x) {
  return __builtin_amdgcn_update_dpp(x, x, CTRL, 0xf, 0xf, false);
}

// VALU cost of a cross-lane xor-mask fetch (DPP/permlane path).
constexpr int dppcost(int ml) {
  int m4 = ml & 15;
  int c = (m4 == 0) ? 0
        : ((m4 == 1 || m4 == 2 || m4 == 3 || m4 == 7 || m4 == 8 || m4 == 15) ? 1 : 2);
  if (ml & 16) c += 2;
  if (ml & 32) c += 2;
  return c;
}

// v[lane ^ ML] on the VALU pipe. quad_perm xor1=0xB1 xor2=0x4E xor3=0x1B;
// row_half_mirror(xor7)=0x141; row_ror:8(xor8)=0x128; row_mirror(xor15)=0x140.
template <int ML>
__device__ __forceinline__ float fetchx(float v) {
  static_assert(ML >= 1 && ML < 64, "lane mask");
  int x = __float_as_int(v);
  constexpr int m4 = ML & 15;
  if constexpr (m4 == 1)       x = dpp_i<0xB1>(x);
  else if constexpr (m4 == 2)  x = dpp_i<0x4E>(x);
  else if constexpr (m4 == 3)  x = dpp_i<0x1B>(x);
  else if constexpr (m4 == 4)  { x = dpp_i<0x141>(x); x = dpp_i<0x1B>(x); }
  else if constexpr (m4 == 5)  { x = dpp_i<0x141>(x); x = dpp_i<0x4E>(x); }
  else if constexpr (m4 == 6)  { x = dpp_i<0x141>(x); x = dpp_i<0xB1>(x); }
  else if constexpr (m4 == 7)  x = dpp_i<0x141>(x);
  else if constexpr (m4 == 8)  x = dpp_i<0x128>(x);
  else if constexpr (m4 == 9)  { x = dpp_i<0x128>(x); x = dpp_i<0xB1>(x); }
  else if constexpr (m4 == 10) { x = dpp_i<0x128>(x); x = dpp_i<0x4E>(x); }
  else if constexpr (m4 == 11) { x = dpp_i<0x128>(x); x = dpp_i<0x1B>(x); }
  else if constexpr (m4 == 12) { x = dpp_i<0x140>(x); x = dpp_i<0x1B>(x); }
  else if constexpr (m4 == 13) { x = dpp_i<0x140>(x); x = dpp_i<0x4E>(x); }
  else if constexpr (m4 == 14) { x = dpp_i<0x140>(x); x = dpp_i<0xB1>(x); }
  else if constexpr (m4 == 15) x = dpp_i<0x140>(x);
  if constexpr (ML & 16) {
    v2i r = __builtin_amdgcn_permlane16_swap(x, x, false, false);
    x = (threadIdx.x & 16) ? r.x : r.y;
  }
  if constexpr (ML & 32) {
    v2i r = __builtin_amdgcn_permlane32_swap(x, x, false, false);
    x = (threadIdx.x & 32) ? r.x : r.y;
  }
  return __int_as_float(x);
}

// 64-lane sum of acc.x + acc.y.
__device__ __forceinline__ float redl(v2f acc) {
  float s = acc.x + acc.y;
  {
    v2i r = __builtin_amdgcn_permlane32_swap(__float_as_int(s),
                                             __float_as_int(s), false, false);
    s = __int_as_float(r.x) + __int_as_float(r.y);
  }
  {
    v2i r = __builtin_amdgcn_permlane16_swap(__float_as_int(s),
                                             __float_as_int(s), false, false);
    s = __int_as_float(r.x) + __int_as_float(r.y);
  }
  s += fetchx<8>(s);
  s += fetchx<4>(s);
  s += fetchx<2>(s);
  s += fetchx<1>(s);
  return s;
}

// Accumulate +-phi_g into W[m & 15]; sign = parity(tid & ((m>>4) & 0xFF)).
template <int G>
__device__ __forceinline__ void accum_signs(float (&W)[16],
                                            const float* __restrict__ phi,
                                            int tid) {
  if constexpr (G < NGATES) {
    constexpr unsigned m = MK.rx[G];
    constexpr int mlo = (int)(m & 15u);
    constexpr int tmask = (int)((m >> 4) & 0xFFu);
    const float th = phi[G];                 // uniform -> s_load, SGPR
    if constexpr (tmask == 0) {
      W[mlo] += th;
    } else {
      const int sgn = (__popc(tid & tmask) & 1) << 31;
      W[mlo] += __int_as_float(__float_as_int(th) ^ sgn);
    }
    accum_signs<G + 1>(W, phi, tid);
  }
}

// Is correlation lag w handled via the LDS stash?
constexpr bool is_lds(int w) {
  unsigned zm = MK.z[w];
  int tz = (int)((zm >> 4) & 0xFFu);
  return (tz >> 6) != 0 || dppcost(tz & 63) > 2;
}

// Cheap lags: partner via DPP/permlane (lane bits only), 16-amp dot, reduce.
template <int W_>
__device__ __forceinline__ void corr_dpp(const v2f (&st)[16], float* zb,
                                         int lane, int wv) {
  if constexpr (W_ < NQ) {
    if constexpr (!is_lds(W_)) {
      constexpr unsigned zm = MK.z[W_];
      constexpr int mr = (int)(zm & 15u);
      constexpr int ml = (int)((zm >> 4) & 63u);
      v2f acc; acc.x = 0.f; acc.y = 0.f;
#pragma unroll
      for (int r = 0; r < 16; ++r) {
        v2f t;
        if constexpr (ml == 0) t = st[r ^ mr];
        else { t.x = fetchx<ml>(st[r ^ mr].x); t.y = fetchx<ml>(st[r ^ mr].y); }
        acc += st[r] * t;                    // v_pk_fma_f32
      }
      float s = redl(acc);
      if (lane == 0) zb[wv * NQ + W_] = s;
    }
    corr_dpp<W_ + 1>(st, zb, lane, wv);
  }
}

// LDS-stash lags: full st stashed once (slot k, thread t at xbuf[k*256+t]).
// Partner thread = tid ^ ((zm>>4) & 0xFF); slot k serves local reg k^mr.
template <int W_>
__device__ __forceinline__ void corr_lds(const v2f (&st)[16],
                                         const v2f* xbuf, float* zb,
                                         int tid, int lane, int wv) {
  if constexpr (W_ < NQ) {
    if constexpr (is_lds(W_)) {
      constexpr unsigned zm = MK.z[W_];
      constexpr int mr = (int)(zm & 15u);
      constexpr int tz = (int)((zm >> 4) & 0xFFu);
      const int ptid = tid ^ tz;
      v2f acc; acc.x = 0.f; acc.y = 0.f;
#pragma unroll
      for (int k = 0; k < 16; ++k)
        acc += st[k] * xbuf[(k ^ mr) * 256 + ptid];
      float s = redl(acc);
      if (lane == 0) zb[wv * NQ + W_] = s;
    }
    corr_lds<W_ + 1>(st, xbuf, zb, tid, lane, wv);
  }
}

// Prep: 48 batch-uniform gate angles -> th_g/(4pi) (revolutions of th/2).
__global__ void prep_kernel(const float* __restrict__ wts,
                            float* __restrict__ phi) {
  const int i = threadIdx.x;
  if (i < NGATES) phi[i] = wts[i] * (0.5f * INV_2PI);
}

__global__ __attribute__((amdgpu_flat_work_group_size(256, 256),
                          amdgpu_waves_per_eu(4)))
void qsim_kernel(const float* __restrict__ x,
                 const float* __restrict__ phi,
                 float* __restrict__ out) {
  __shared__ v2f xbuf[16 * 256];       // 32 KiB full-state stash
  __shared__ float zb[4 * NQ];

  const int bidx = blockIdx.x;         // one batch element per 256-thr block
  const int tid  = threadIdx.x;
  const int lane = tid & 63;
  const int wv   = tid >> 6;

  const float4* xv = reinterpret_cast<const float4*>(x + bidx * NQ);
  float4 q0 = xv[0], q1 = xv[1], q2 = xv[2];
  const float xa[NQ] = {q0.x, q0.y, q0.z, q0.w, q1.x, q1.y, q1.z, q1.w,
                        q2.x, q2.y, q2.z, q2.w};

  // ---- Phase 1: real product amplitude A (a0 = cy+sy, a1 = cy-sy).
  // Scalar: qubit 0 = tid7, qubit 1 = tid6, qubits 2..7 = tid bits 5..0.
  float A[16];
  {
    float rv = xa[0] * (0.5f * INV_2PI);
    float sy = __builtin_amdgcn_sinf(rv), cy = __builtin_amdgcn_cosf(rv);
    float F = 0.015625f * (((tid >> 7) & 1) ? (cy - sy) : (cy + sy));  // 2^-6
    rv = xa[1] * (0.5f * INV_2PI);
    sy = __builtin_amdgcn_sinf(rv); cy = __builtin_amdgcn_cosf(rv);
    F *= ((tid >> 6) & 1) ? (cy - sy) : (cy + sy);
#pragma unroll
    for (int w = 2; w <= 7; ++w) {
      rv = xa[w] * (0.5f * INV_2PI);
      sy = __builtin_amdgcn_sinf(rv); cy = __builtin_amdgcn_cosf(rv);
      F *= ((tid >> (7 - w)) & 1) ? (cy - sy) : (cy + sy);
    }
    A[0] = F;
#pragma unroll
    for (int j = 0; j < 4; ++j) {                // reg bit j = qubit 11-j
      const int wq = 11 - j;
      rv = xa[wq] * (0.5f * INV_2PI);
      sy = __builtin_amdgcn_sinf(rv); cy = __builtin_amdgcn_cosf(rv);
      const float g0 = cy + sy, g1 = cy - sy;
#pragma unroll
      for (int k = 0; k < 8; ++k) {
        if (k < (1 << j)) {
          float base = A[k];
          A[k | (1 << j)] = base * g1;
          A[k]            = base * g0;
        }
      }
    }
  }

  // ---- Phase 2: Phi via signed accumulation + 4-bit WHT over reg coords.
  float W[16];
#pragma unroll
  for (int k = 0; k < 16; ++k) W[k] = 0.f;
  accum_signs<0>(W, phi, tid);
#pragma unroll
  for (int j = 0; j < 4; ++j) {
#pragma unroll
    for (int k = 0; k < 16; ++k) {
      if (!(k & (1 << j))) {
        float a = W[k], b = W[k | (1 << j)];
        W[k]            = a + b;
        W[k | (1 << j)] = a - b;
      }
    }
  }

  // ---- Phase 3: psi = A e^{-i Phi}; A and W die into st (32 VGPRs).
  v2f st[16];
#pragma unroll
  for (int r = 0; r < 16; ++r) {
    float s = __builtin_amdgcn_sinf(W[r]);
    float c = __builtin_amdgcn_cosf(W[r]);
    st[r].x = A[r] * c;
    st[r].y = -A[r] * s;
  }

  // ---- Phase 4: <Z_w> = sum_q Re[psi*(q^rho_w) psi(q)].
  corr_dpp<0>(st, zb, lane, wv);

#pragma unroll
  for (int k = 0; k < 16; ++k) xbuf[k * 256 + tid] = st[k];
  __syncthreads();
  corr_lds<0>(st, xbuf, zb, tid, lane, wv);

  __syncthreads();
  if (tid < NQ)
    out[bidx * NQ + tid] =
        zb[tid] + zb[NQ + tid] + zb[2 * NQ + tid] + zb[3 * NQ + tid];
}

extern "C" void kernel_launch(void* const* d_in, const int* in_sizes, int n_in,
                              void* d_out, int out_size, void* d_ws, size_t ws_size,
                              hipStream_t stream) {
  const float* x   = (const float*)d_in[0];   // (4096, 12) f32
  const float* wts = (const float*)d_in[1];   // (4, 12) f32
  float* out = (float*)d_out;                 // (4096, 12) f32
  float* phi = (float*)d_ws;                  // 48 floats: th/(4pi)

  prep_kernel<<<1, 64, 0, stream>>>(wts, phi);

  const int batch = in_sizes[0] / NQ;         // 4096
  dim3 grid(batch);
  dim3 block(256);
  qsim_kernel<<<grid, block, 0, stream>>>(x, phi, out);
}

// Round 15
// 38.217 us; speedup vs baseline: 4.4554x; 2.0472x over previous
//
#include <hip/hip_runtime.h>

#define NQ 12
#define NL 4
#define NGATES (NQ * NL)
#define INV_2PI 0.15915494309189535f

// ---------------------------------------------------------------------------
// Diagonalized formulation (round-12 algebra, 16 amps/thread).
// Every compiled gate is exp(-i th/2 X_m) -> all 48 commute; conjugating by
// H^x12 diagonalizes the circuit: U = H D H, D|q> = e^{-iPhi(q)}|q>,
//   Phi(q) = sum_g (th_g/2)(-1)^{parity(q & m_g)}  (layer-1 included).
// <Z_w> = sum_q conj(psi(q^rho_w)) psi(q), rho_w = row of L^-1 (HZH = X);
// psi = A e^{-iPhi}, A real product state (a0 = cy+sy, a1 = cy-sy, scale 2^-6).
// Layout (A = I): p[3:0] = reg (qubits 11..8), p[9:4] = lane bits 0..5
// (qubits 7..2), p[10] = tid6 (qubit 1), p[11] = tid7 (qubit 0).
// 256 thr/elem, 16 amps/thread: st = 32 VGPR, A/W 16 each.
// waves_per_eu(3): round-14 used (4) -> 128-unified budget split 64 arch +
// 64 acc; ~45 floats/thread of transient overflow went to SCRATCH (280 MB
// of HBM traffic at 3.7 TB/s = the entire 78 us runtime). wpe(3) (~170
// budget) grants arch ~76+ with AGPR overflow and zero scratch (r11 data).
// Phi: accumulate +-phi_g into W[m&15] (sign = parity(tid & (m>>4))), 4-bit
// WHT, then st[r] = A[r](cos, -sin)(W[r]) via hw trig in revolutions.
// Correlations: cheap lane masks via DPP/permlane; others via ONE full LDS
// stash of st (32 KB, one barrier), each lag computed and retired in turn.
// ---------------------------------------------------------------------------
struct Masks { unsigned rx[NGATES]; unsigned z[NQ]; };

constexpr Masks compute_masks() {
  Masks mk{};
  unsigned col[NQ] = {};
  for (int b = 0; b < NQ; ++b) col[b] = 1u << b;
  int g = 0;
  for (int l = 0; l < NL; ++l) {
    for (int w = 0; w < NQ; ++w) mk.rx[g++] = col[NQ - 1 - w];
    for (int i = 0; i < NQ; ++i) {           // ring CNOT(i, (i+1)%12)
      int cb = NQ - 1 - i;
      int tb = NQ - 1 - ((i + 1) % NQ);
      col[cb] ^= col[tb];
    }
  }
  unsigned A[NQ] = {}, Inv[NQ] = {};
  for (int i = 0; i < NQ; ++i) {
    unsigned rowv = 0;
    for (int j = 0; j < NQ; ++j) rowv |= ((col[j] >> i) & 1u) << j;
    A[i] = rowv;
    Inv[i] = 1u << i;
  }
  for (int c = 0; c < NQ; ++c) {
    int piv = c;
    while (((A[piv] >> c) & 1u) == 0u) ++piv;
    unsigned ta = A[piv]; A[piv] = A[c]; A[c] = ta;
    unsigned ti = Inv[piv]; Inv[piv] = Inv[c]; Inv[c] = ti;
    for (int r = 0; r < NQ; ++r)
      if (r != c && ((A[r] >> c) & 1u)) { A[r] ^= A[c]; Inv[r] ^= Inv[c]; }
  }
  for (int w = 0; w < NQ; ++w) mk.z[w] = Inv[NQ - 1 - w];
  return mk;
}

constexpr Masks MK = compute_masks();

typedef float v2f __attribute__((ext_vector_type(2)));
typedef int   v2i __attribute__((ext_vector_type(2)));

template <int CTRL>
__device__ __forceinline__ int dpp_i(int x) {
  return __builtin_amdgcn_update_dpp(x, x, CTRL, 0xf, 0xf, false);
}

// VALU cost of a cross-lane xor-mask fetch (DPP/permlane path).
constexpr int dppcost(int ml) {
  int m4 = ml & 15;
  int c = (m4 == 0) ? 0
        : ((m4 == 1 || m4 == 2 || m4 == 3 || m4 == 7 || m4 == 8 || m4 == 15) ? 1 : 2);
  if (ml & 16) c += 2;
  if (ml & 32) c += 2;
  return c;
}

// v[lane ^ ML] on the VALU pipe. quad_perm xor1=0xB1 xor2=0x4E xor3=0x1B;
// row_half_mirror(xor7)=0x141; row_ror:8(xor8)=0x128; row_mirror(xor15)=0x140.
template <int ML>
__device__ __forceinline__ float fetchx(float v) {
  static_assert(ML >= 1 && ML < 64, "lane mask");
  int x = __float_as_int(v);
  constexpr int m4 = ML & 15;
  if constexpr (m4 == 1)       x = dpp_i<0xB1>(x);
  else if constexpr (m4 == 2)  x = dpp_i<0x4E>(x);
  else if constexpr (m4 == 3)  x = dpp_i<0x1B>(x);
  else if constexpr (m4 == 4)  { x = dpp_i<0x141>(x); x = dpp_i<0x1B>(x); }
  else if constexpr (m4 == 5)  { x = dpp_i<0x141>(x); x = dpp_i<0x4E>(x); }
  else if constexpr (m4 == 6)  { x = dpp_i<0x141>(x); x = dpp_i<0xB1>(x); }
  else if constexpr (m4 == 7)  x = dpp_i<0x141>(x);
  else if constexpr (m4 == 8)  x = dpp_i<0x128>(x);
  else if constexpr (m4 == 9)  { x = dpp_i<0x128>(x); x = dpp_i<0xB1>(x); }
  else if constexpr (m4 == 10) { x = dpp_i<0x128>(x); x = dpp_i<0x4E>(x); }
  else if constexpr (m4 == 11) { x = dpp_i<0x128>(x); x = dpp_i<0x1B>(x); }
  else if constexpr (m4 == 12) { x = dpp_i<0x140>(x); x = dpp_i<0x1B>(x); }
  else if constexpr (m4 == 13) { x = dpp_i<0x140>(x); x = dpp_i<0x4E>(x); }
  else if constexpr (m4 == 14) { x = dpp_i<0x140>(x); x = dpp_i<0xB1>(x); }
  else if constexpr (m4 == 15) x = dpp_i<0x140>(x);
  if constexpr (ML & 16) {
    v2i r = __builtin_amdgcn_permlane16_swap(x, x, false, false);
    x = (threadIdx.x & 16) ? r.x : r.y;
  }
  if constexpr (ML & 32) {
    v2i r = __builtin_amdgcn_permlane32_swap(x, x, false, false);
    x = (threadIdx.x & 32) ? r.x : r.y;
  }
  return __int_as_float(x);
}

// 64-lane sum of acc.x + acc.y.
__device__ __forceinline__ float redl(v2f acc) {
  float s = acc.x + acc.y;
  {
    v2i r = __builtin_amdgcn_permlane32_swap(__float_as_int(s),
                                             __float_as_int(s), false, false);
    s = __int_as_float(r.x) + __int_as_float(r.y);
  }
  {
    v2i r = __builtin_amdgcn_permlane16_swap(__float_as_int(s),
                                             __float_as_int(s), false, false);
    s = __int_as_float(r.x) + __int_as_float(r.y);
  }
  s += fetchx<8>(s);
  s += fetchx<4>(s);
  s += fetchx<2>(s);
  s += fetchx<1>(s);
  return s;
}

// Accumulate +-phi_g into W[m & 15]; sign = parity(tid & ((m>>4) & 0xFF)).
template <int G>
__device__ __forceinline__ void accum_signs(float (&W)[16],
                                            const float* __restrict__ phi,
                                            int tid) {
  if constexpr (G < NGATES) {
    constexpr unsigned m = MK.rx[G];
    constexpr int mlo = (int)(m & 15u);
    constexpr int tmask = (int)((m >> 4) & 0xFFu);
    const float th = phi[G];                 // uniform -> s_load, SGPR
    if constexpr (tmask == 0) {
      W[mlo] += th;
    } else {
      const int sgn = (__popc(tid & tmask) & 1) << 31;
      W[mlo] += __int_as_float(__float_as_int(th) ^ sgn);
    }
    accum_signs<G + 1>(W, phi, tid);
  }
}

// Is correlation lag w handled via the LDS stash?
constexpr bool is_lds(int w) {
  unsigned zm = MK.z[w];
  int tz = (int)((zm >> 4) & 0xFFu);
  return (tz >> 6) != 0 || dppcost(tz & 63) > 2;
}

// Cheap lags: partner via DPP/permlane (lane bits only), 16-amp dot, reduce.
template <int W_>
__device__ __forceinline__ void corr_dpp(const v2f (&st)[16], float* zb,
                                         int lane, int wv) {
  if constexpr (W_ < NQ) {
    if constexpr (!is_lds(W_)) {
      constexpr unsigned zm = MK.z[W_];
      constexpr int mr = (int)(zm & 15u);
      constexpr int ml = (int)((zm >> 4) & 63u);
      v2f acc; acc.x = 0.f; acc.y = 0.f;
#pragma unroll
      for (int r = 0; r < 16; ++r) {
        v2f t;
        if constexpr (ml == 0) t = st[r ^ mr];
        else { t.x = fetchx<ml>(st[r ^ mr].x); t.y = fetchx<ml>(st[r ^ mr].y); }
        acc += st[r] * t;                    // v_pk_fma_f32
      }
      float s = redl(acc);
      if (lane == 0) zb[wv * NQ + W_] = s;
    }
    corr_dpp<W_ + 1>(st, zb, lane, wv);
  }
}

// LDS-stash lags: full st stashed once (slot k, thread t at xbuf[k*256+t]).
// Partner thread = tid ^ ((zm>>4) & 0xFF); slot k serves local reg k^mr.
template <int W_>
__device__ __forceinline__ void corr_lds(const v2f (&st)[16],
                                         const v2f* xbuf, float* zb,
                                         int tid, int lane, int wv) {
  if constexpr (W_ < NQ) {
    if constexpr (is_lds(W_)) {
      constexpr unsigned zm = MK.z[W_];
      constexpr int mr = (int)(zm & 15u);
      constexpr int tz = (int)((zm >> 4) & 0xFFu);
      const int ptid = tid ^ tz;
      v2f acc; acc.x = 0.f; acc.y = 0.f;
#pragma unroll
      for (int k = 0; k < 16; ++k)
        acc += st[k] * xbuf[(k ^ mr) * 256 + ptid];
      float s = redl(acc);
      if (lane == 0) zb[wv * NQ + W_] = s;
    }
    corr_lds<W_ + 1>(st, xbuf, zb, tid, lane, wv);
  }
}

// Prep: 48 batch-uniform gate angles -> th_g/(4pi) (revolutions of th/2).
__global__ void prep_kernel(const float* __restrict__ wts,
                            float* __restrict__ phi) {
  const int i = threadIdx.x;
  if (i < NGATES) phi[i] = wts[i] * (0.5f * INV_2PI);
}

__global__ __attribute__((amdgpu_flat_work_group_size(256, 256),
                          amdgpu_waves_per_eu(3)))
void qsim_kernel(const float* __restrict__ x,
                 const float* __restrict__ phi,
                 float* __restrict__ out) {
  __shared__ v2f xbuf[16 * 256];       // 32 KiB full-state stash
  __shared__ float zb[4 * NQ];

  const int bidx = blockIdx.x;         // one batch element per 256-thr block
  const int tid  = threadIdx.x;
  const int lane = tid & 63;
  const int wv   = tid >> 6;

  const float4* xv = reinterpret_cast<const float4*>(x + bidx * NQ);
  float4 q0 = xv[0], q1 = xv[1], q2 = xv[2];
  const float xa[NQ] = {q0.x, q0.y, q0.z, q0.w, q1.x, q1.y, q1.z, q1.w,
                        q2.x, q2.y, q2.z, q2.w};

  // ---- Phase 1: real product amplitude A (a0 = cy+sy, a1 = cy-sy).
  // Scalar: qubit 0 = tid7, qubit 1 = tid6, qubits 2..7 = tid bits 5..0.
  float A[16];
  {
    float rv = xa[0] * (0.5f * INV_2PI);
    float sy = __builtin_amdgcn_sinf(rv), cy = __builtin_amdgcn_cosf(rv);
    float F = 0.015625f * (((tid >> 7) & 1) ? (cy - sy) : (cy + sy));  // 2^-6
    rv = xa[1] * (0.5f * INV_2PI);
    sy = __builtin_amdgcn_sinf(rv); cy = __builtin_amdgcn_cosf(rv);
    F *= ((tid >> 6) & 1) ? (cy - sy) : (cy + sy);
#pragma unroll
    for (int w = 2; w <= 7; ++w) {
      rv = xa[w] * (0.5f * INV_2PI);
      sy = __builtin_amdgcn_sinf(rv); cy = __builtin_amdgcn_cosf(rv);
      F *= ((tid >> (7 - w)) & 1) ? (cy - sy) : (cy + sy);
    }
    A[0] = F;
#pragma unroll
    for (int j = 0; j < 4; ++j) {                // reg bit j = qubit 11-j
      const int wq = 11 - j;
      rv = xa[wq] * (0.5f * INV_2PI);
      sy = __builtin_amdgcn_sinf(rv); cy = __builtin_amdgcn_cosf(rv);
      const float g0 = cy + sy, g1 = cy - sy;
#pragma unroll
      for (int k = 0; k < 8; ++k) {
        if (k < (1 << j)) {
          float base = A[k];
          A[k | (1 << j)] = base * g1;
          A[k]            = base * g0;
        }
      }
    }
  }

  // ---- Phase 2: Phi via signed accumulation + 4-bit WHT over reg coords.
  float W[16];
#pragma unroll
  for (int k = 0; k < 16; ++k) W[k] = 0.f;
  accum_signs<0>(W, phi, tid);
#pragma unroll
  for (int j = 0; j < 4; ++j) {
#pragma unroll
    for (int k = 0; k < 16; ++k) {
      if (!(k & (1 << j))) {
        float a = W[k], b = W[k | (1 << j)];
        W[k]            = a + b;
        W[k | (1 << j)] = a - b;
      }
    }
  }

  // ---- Phase 3: psi = A e^{-i Phi}; A and W die into st (32 VGPRs).
  v2f st[16];
#pragma unroll
  for (int r = 0; r < 16; ++r) {
    float s = __builtin_amdgcn_sinf(W[r]);
    float c = __builtin_amdgcn_cosf(W[r]);
    st[r].x = A[r] * c;
    st[r].y = -A[r] * s;
  }

  // ---- Phase 4: <Z_w> = sum_q Re[psi*(q^rho_w) psi(q)].
  corr_dpp<0>(st, zb, lane, wv);

#pragma unroll
  for (int k = 0; k < 16; ++k) xbuf[k * 256 + tid] = st[k];
  __syncthreads();
  corr_lds<0>(st, xbuf, zb, tid, lane, wv);

  __syncthreads();
  if (tid < NQ)
    out[bidx * NQ + tid] =
        zb[tid] + zb[NQ + tid] + zb[2 * NQ + tid] + zb[3 * NQ + tid];
}

extern "C" void kernel_launch(void* const* d_in, const int* in_sizes, int n_in,
                              void* d_out, int out_size, void* d_ws, size_t ws_size,
                              hipStream_t stream) {
  const float* x   = (const float*)d_in[0];   // (4096, 12) f32
  const float* wts = (const float*)d_in[1];   // (4, 12) f32
  float* out = (float*)d_out;                 // (4096, 12) f32
  float* phi = (float*)d_ws;                  // 48 floats: th/(4pi)

  prep_kernel<<<1, 64, 0, stream>>>(wts, phi);

  const int batch = in_sizes[0] / NQ;         // 4096
  dim3 grid(batch);
  dim3 block(256);
  qsim_kernel<<<grid, block, 0, stream>>>(x, phi, out);
}